// Round 1
// baseline (1121.767 us; speedup 1.0000x reference)
//
#include <hip/hip_runtime.h>

#define DEV static __device__ __forceinline__

typedef __bf16 bf16;
typedef __bf16 bf16x8 __attribute__((ext_vector_type(8)));
typedef float f32x4 __attribute__((ext_vector_type(4)));

static_assert(sizeof(bf16x8) == 16, "bf16x8 must be 16B");

// ---------------- async global->LDS, 16B/lane, wave-uniform LDS base ----------------
DEV void gll16(const void* g, void* l) {
  __builtin_amdgcn_global_load_lds(
      (const __attribute__((address_space(1))) unsigned int*)g,
      (__attribute__((address_space(3))) unsigned int*)l, 16, 0, 0);
}

// ---------------- transpose + fp32 -> bf16 (hi, optional lo) ----------------
// src: [z][R][C] fp32 ; dst hi/lo: [z][C][R] bf16
__global__ void transpose_cvt_kernel(const float* __restrict__ src, bf16* __restrict__ hi,
                                     bf16* __restrict__ lo, int R, int C) {
  __shared__ float t[32][33];
  const int z = blockIdx.z;
  const size_t zoff = (size_t)z * R * C;
  const int c0 = blockIdx.x * 32, r0 = blockIdx.y * 32;
  const int tid = threadIdx.x;
#pragma unroll
  for (int i = 0; i < 4; ++i) {
    int idx = tid + i * 256;
    int r = idx >> 5, c = idx & 31;
    t[r][c] = src[zoff + (size_t)(r0 + r) * C + (c0 + c)];
  }
  __syncthreads();
#pragma unroll
  for (int i = 0; i < 4; ++i) {
    int idx = tid + i * 256;
    int c = idx >> 5, r = idx & 31;
    float v = t[r][c];
    bf16 h = (bf16)v;
    size_t o = zoff + (size_t)(c0 + c) * R + (r0 + r);
    hi[o] = h;
    if (lo) lo[o] = (bf16)(v - (float)h);
  }
}

// ---------------- block reduction helper (2 values, 256 threads) ----------------
DEV void block_reduce2(float& a, float& b, float* red, int tid) {
#pragma unroll
  for (int m = 32; m >= 1; m >>= 1) {
    a += __shfl_xor(a, m);
    b += __shfl_xor(b, m);
  }
  if ((tid & 63) == 0) {
    red[(tid >> 6) * 2] = a;
    red[(tid >> 6) * 2 + 1] = b;
  }
  __syncthreads();
  a = red[0] + red[2] + red[4] + red[6];
  b = red[1] + red[3] + red[5] + red[7];
}

// ---------------- LayerNorm -> bf16 hi/lo split ----------------
__global__ void ln_split_kernel(const float* __restrict__ x, const float* __restrict__ g,
                                const float* __restrict__ bb, bf16* __restrict__ hi,
                                bf16* __restrict__ lo) {
  __shared__ float red[8];
  const int n = blockIdx.x, tid = threadIdx.x;
  const float* row = x + (size_t)n * 1024;
  float4 v = *(const float4*)(row + tid * 4);
  float s = v.x + v.y + v.z + v.w;
  float ss = v.x * v.x + v.y * v.y + v.z * v.z + v.w * v.w;
  block_reduce2(s, ss, red, tid);
  float mean = s * (1.f / 1024.f);
  float var = ss * (1.f / 1024.f) - mean * mean;
  float rstd = rsqrtf(var + 1e-5f);
  float vv[4] = {v.x, v.y, v.z, v.w};
#pragma unroll
  for (int c = 0; c < 4; ++c) {
    int col = tid * 4 + c;
    float y = (vv[c] - mean) * rstd * g[col] + bb[col];
    bf16 h = (bf16)y;
    size_t o = (size_t)n * 1024 + col;
    hi[o] = h;
    lo[o] = (bf16)(y - (float)h);
  }
}

// ---------------- x3-precision GEMM: C[M,N] = A[M,K] * B^T[N,K] (+ addend) ----------------
// A = Ah+Al, B = Bh+Bl (bf16 splits of fp32). acc += Ah*Bh + Ah*Bl + Al*Bh.
__global__ __launch_bounds__(256, 2) void gemm_x3_kernel(
    const bf16* __restrict__ Ah, const bf16* __restrict__ Al, const bf16* __restrict__ Bh,
    const bf16* __restrict__ Bl, const float* __restrict__ addend, float* __restrict__ C, int M,
    int N, int K) {
  __shared__ bf16 As_h[128 * 64];
  __shared__ bf16 As_l[128 * 64];
  __shared__ bf16 Bs_h[128 * 64];
  __shared__ bf16 Bs_l[128 * 64];
  const int tid = threadIdx.x;
  const int w = tid >> 6, lane = tid & 63;
  const int quad = lane >> 4, l15 = lane & 15;
  const int m0 = blockIdx.y * 128, n0 = blockIdx.x * 128;
  const int wm = (w >> 1) * 64, wn = (w & 1) * 64;
  const int r8 = lane >> 3, c8 = lane & 7;

  size_t gA[4], gB[4];
  unsigned lbase[4];
#pragma unroll
  for (int i = 0; i < 4; ++i) {
    int rr = ((w * 4 + i) << 3) + r8;
    gA[i] = (size_t)(m0 + rr) * K + (c8 << 3);
    gB[i] = (size_t)(n0 + rr) * K + (c8 << 3);
    lbase[i] = (unsigned)((w * 4 + i) << 9);  // elements; HW adds lane*16B
  }
  const f32x4 fz = {0.f, 0.f, 0.f, 0.f};
  f32x4 acc[4][4];
#pragma unroll
  for (int a = 0; a < 4; ++a)
#pragma unroll
    for (int b = 0; b < 4; ++b) acc[a][b] = fz;

  for (int k0 = 0; k0 < K; k0 += 64) {
#pragma unroll
    for (int i = 0; i < 4; ++i) {
      gll16(Ah + gA[i] + k0, As_h + lbase[i]);
      gll16(Al + gA[i] + k0, As_l + lbase[i]);
      gll16(Bh + gB[i] + k0, Bs_h + lbase[i]);
      gll16(Bl + gB[i] + k0, Bs_l + lbase[i]);
    }
    __syncthreads();
#pragma unroll
    for (int ks = 0; ks < 2; ++ks) {
      bf16x8 a_h[4], a_l[4], b_h[4], b_l[4];
#pragma unroll
      for (int mi = 0; mi < 4; ++mi) {
        int off = (wm + mi * 16 + l15) * 64 + ks * 32 + quad * 8;
        a_h[mi] = *(const bf16x8*)(As_h + off);
        a_l[mi] = *(const bf16x8*)(As_l + off);
      }
#pragma unroll
      for (int ni = 0; ni < 4; ++ni) {
        int off = (wn + ni * 16 + l15) * 64 + ks * 32 + quad * 8;
        b_h[ni] = *(const bf16x8*)(Bs_h + off);
        b_l[ni] = *(const bf16x8*)(Bs_l + off);
      }
#pragma unroll
      for (int mi = 0; mi < 4; ++mi)
#pragma unroll
        for (int ni = 0; ni < 4; ++ni) {
          acc[mi][ni] = __builtin_amdgcn_mfma_f32_16x16x32_bf16(a_h[mi], b_h[ni], acc[mi][ni], 0, 0, 0);
          acc[mi][ni] = __builtin_amdgcn_mfma_f32_16x16x32_bf16(a_h[mi], b_l[ni], acc[mi][ni], 0, 0, 0);
          acc[mi][ni] = __builtin_amdgcn_mfma_f32_16x16x32_bf16(a_l[mi], b_h[ni], acc[mi][ni], 0, 0, 0);
        }
    }
    __syncthreads();
  }
#pragma unroll
  for (int mi = 0; mi < 4; ++mi)
#pragma unroll
    for (int r = 0; r < 4; ++r) {
      int row = m0 + wm + mi * 16 + quad * 4 + r;
      size_t rb = (size_t)row * N;
#pragma unroll
      for (int ni = 0; ni < 4; ++ni) {
        int col = n0 + wn + ni * 16 + l15;
        float v = acc[mi][ni][r];
        if (addend) v += addend[rb + col];
        C[rb + col] = v;
      }
    }
}

// ---------------- fp32 causal flash attention (VALU) ----------------
// qkv: [4096][3072] fp32 (q|k|v). out: bf16 hi/lo [4096][1024].
__global__ __launch_bounds__(256) void attn_kernel(const float* __restrict__ qkv,
                                                   bf16* __restrict__ o_hi,
                                                   bf16* __restrict__ o_lo) {
  __shared__ float Ks[64][64];
  __shared__ float Vs[64][64];
  const int bh = blockIdx.x;
  const int b = bh >> 4, h = bh & 15;
  const int q0 = blockIdx.y * 64;
  const int tid = threadIdx.x;
  const int ql = tid >> 2, sub = tid & 3;
  const size_t rowq = (size_t)(b * 512 + q0 + ql) * 3072 + h * 64 + sub * 16;
  float q[16];
#pragma unroll
  for (int j = 0; j < 16; ++j) q[j] = qkv[rowq + j] * 0.125f;  // fold hd^-0.5
  float m_i = -1e30f, l_i = 0.f;
  float o[16];
#pragma unroll
  for (int j = 0; j < 16; ++j) o[j] = 0.f;
  const int ntiles = blockIdx.y + 1;
  for (int t = 0; t < ntiles; ++t) {
    const int kv0 = t * 64;
    __syncthreads();
    for (int i = tid; i < 1024; i += 256) {
      int r = i >> 4, c4 = (i & 15) << 2;
      const float* kp = qkv + (size_t)(b * 512 + kv0 + r) * 3072 + 1024 + h * 64 + c4;
      *(float4*)&Ks[r][c4] = *(const float4*)kp;
      *(float4*)&Vs[r][c4] = *(const float4*)(kp + 1024);
    }
    __syncthreads();
    const int kvlim = min(64, q0 + ql - kv0 + 1);
    for (int kv = 0; kv < kvlim; ++kv) {
      float s = 0.f;
#pragma unroll
      for (int j = 0; j < 16; ++j) s += q[j] * Ks[kv][sub * 16 + j];
      s += __shfl_xor(s, 1);
      s += __shfl_xor(s, 2);
      float m_new = fmaxf(m_i, s);
      float alpha = __expf(m_i - m_new);
      float p = __expf(s - m_new);
      l_i = l_i * alpha + p;
#pragma unroll
      for (int j = 0; j < 16; ++j) o[j] = o[j] * alpha + p * Vs[kv][sub * 16 + j];
      m_i = m_new;
    }
  }
  const float inv = 1.f / l_i;
  const size_t ob = (size_t)(b * 512 + q0 + ql) * 1024 + h * 64 + sub * 16;
#pragma unroll
  for (int j = 0; j < 16; ++j) {
    float v = o[j] * inv;
    bf16 hh = (bf16)v;
    o_hi[ob + j] = hh;
    o_lo[ob + j] = (bf16)(v - (float)hh);
  }
}

// ---------------- LN2 + gate softmax + top2 routing (fp32, per-token block) ----------------
__global__ void ln2_gate_kernel(const float* __restrict__ xr, const float* __restrict__ g,
                                const float* __restrict__ bb, const float* __restrict__ wg,
                                bf16* __restrict__ moe_b, float* __restrict__ top_w,
                                int* __restrict__ top_i, int* __restrict__ counts) {
  __shared__ float red[8];
  __shared__ float red8[4][8];
  const int n = blockIdx.x, tid = threadIdx.x;
  const float* row = xr + (size_t)n * 1024;
  float4 v = *(const float4*)(row + tid * 4);
  float s = v.x + v.y + v.z + v.w;
  float ss = v.x * v.x + v.y * v.y + v.z * v.z + v.w * v.w;
  block_reduce2(s, ss, red, tid);
  float mean = s * (1.f / 1024.f);
  float var = ss * (1.f / 1024.f) - mean * mean;
  float rstd = rsqrtf(var + 1e-5f);
  float vv[4] = {v.x, v.y, v.z, v.w};
  float a8[8];
#pragma unroll
  for (int e = 0; e < 8; ++e) a8[e] = 0.f;
#pragma unroll
  for (int c = 0; c < 4; ++c) {
    int col = tid * 4 + c;
    float y = (vv[c] - mean) * rstd * g[col] + bb[col];
    moe_b[(size_t)n * 1024 + col] = (bf16)y;
    const float* wr = wg + (size_t)col * 8;
#pragma unroll
    for (int e = 0; e < 8; ++e) a8[e] += y * wr[e];
  }
#pragma unroll
  for (int e = 0; e < 8; ++e)
#pragma unroll
    for (int m = 32; m >= 1; m >>= 1) a8[e] += __shfl_xor(a8[e], m);
  if ((tid & 63) == 0)
#pragma unroll
    for (int e = 0; e < 8; ++e) red8[tid >> 6][e] = a8[e];
  __syncthreads();
  if (tid == 0) {
    float lg[8];
#pragma unroll
    for (int e = 0; e < 8; ++e) lg[e] = red8[0][e] + red8[1][e] + red8[2][e] + red8[3][e];
    float mx = lg[0];
#pragma unroll
    for (int e = 1; e < 8; ++e) mx = fmaxf(mx, lg[e]);
    float pe[8];
#pragma unroll
    for (int e = 0; e < 8; ++e) pe[e] = __expf(lg[e] - mx);
    // top-2, ties -> lower index (matches lax.top_k)
    int i1 = 0;
    float p1 = pe[0];
#pragma unroll
    for (int e = 1; e < 8; ++e)
      if (pe[e] > p1) { p1 = pe[e]; i1 = e; }
    int i2 = -1;
    float p2 = -1.f;
#pragma unroll
    for (int e = 0; e < 8; ++e)
      if (e != i1 && pe[e] > p2) { p2 = pe[e]; i2 = e; }
    float inv = 1.f / (p1 + p2);  // softmax denom cancels in renormalization
    top_w[n * 2] = p1 * inv;
    top_w[n * 2 + 1] = p2 * inv;
    top_i[n * 2] = i1;
    top_i[n * 2 + 1] = i2;
    atomicAdd(&counts[i1], 1);
    atomicAdd(&counts[i2], 1);
  }
}

__global__ void offsets_kernel(const int* __restrict__ counts, int* __restrict__ offs) {
  if (threadIdx.x == 0 && blockIdx.x == 0) {
    int a = 0;
    for (int e = 0; e < 8; ++e) {
      offs[e] = a;
      a += counts[e];
    }
  }
}

__global__ void scatter_kernel(const int* __restrict__ top_i, const int* __restrict__ offs,
                               int* __restrict__ cursor, int* __restrict__ expert_tok,
                               int* __restrict__ inv_slot) {
  int n = blockIdx.x * 256 + threadIdx.x;
  if (n >= 4096) return;
#pragma unroll
  for (int k = 0; k < 2; ++k) {
    int e = top_i[n * 2 + k];
    int pos = atomicAdd(&cursor[e], 1);
    int slot = offs[e] + pos;
    expert_tok[slot] = n;
    inv_slot[n * 2 + k] = slot;
  }
}

DEV float gelu_tanh(float x) {
  float x3 = x * x * x;
  float t = tanhf(0.7978845608028654f * (x + 0.044715f * x3));
  return 0.5f * x * (1.f + t);
}

// ---------------- MoE GEMM: Out[slot,N](bf16) = act(A_gather[M,K] * B^T[e][N,K] + bias[e]) ----------------
template <int GELU>
__global__ __launch_bounds__(256, 2) void gemm_moe_kernel(
    const bf16* __restrict__ A, const bf16* __restrict__ B, const float* __restrict__ bias,
    const int* __restrict__ counts, const int* __restrict__ offs, const int* __restrict__ gather,
    bf16* __restrict__ Out, int N, int K) {
  __shared__ bf16 As[128 * 64];
  __shared__ bf16 Bs[128 * 64];
  const int e = blockIdx.z;
  const int rows = counts[e];
  const int m0 = blockIdx.y * 128;
  if (m0 >= rows) return;
  const int off = offs[e];
  const int tid = threadIdx.x;
  const int w = tid >> 6, lane = tid & 63;
  const int quad = lane >> 4, l15 = lane & 15;
  const int n0 = blockIdx.x * 128;
  const int wm = (w >> 1) * 64, wn = (w & 1) * 64;
  const int r8 = lane >> 3, c8 = lane & 7;

  size_t gA[4], gB[4];
  unsigned lbase[4];
  const size_t bexp = (size_t)e * N * K;
#pragma unroll
  for (int i = 0; i < 4; ++i) {
    int rr = ((w * 4 + i) << 3) + r8;
    int lr = min(m0 + rr, rows - 1);
    int arow = gather ? gather[off + lr] : (off + lr);
    gA[i] = (size_t)arow * K + (c8 << 3);
    gB[i] = bexp + (size_t)(n0 + rr) * K + (c8 << 3);
    lbase[i] = (unsigned)((w * 4 + i) << 9);
  }
  const f32x4 fz = {0.f, 0.f, 0.f, 0.f};
  f32x4 acc[4][4];
#pragma unroll
  for (int a = 0; a < 4; ++a)
#pragma unroll
    for (int b = 0; b < 4; ++b) acc[a][b] = fz;

  for (int k0 = 0; k0 < K; k0 += 64) {
#pragma unroll
    for (int i = 0; i < 4; ++i) {
      gll16(A + gA[i] + k0, As + lbase[i]);
      gll16(B + gB[i] + k0, Bs + lbase[i]);
    }
    __syncthreads();
#pragma unroll
    for (int ks = 0; ks < 2; ++ks) {
      bf16x8 af[4], bf_[4];
#pragma unroll
      for (int mi = 0; mi < 4; ++mi)
        af[mi] = *(const bf16x8*)(As + (wm + mi * 16 + l15) * 64 + ks * 32 + quad * 8);
#pragma unroll
      for (int ni = 0; ni < 4; ++ni)
        bf_[ni] = *(const bf16x8*)(Bs + (wn + ni * 16 + l15) * 64 + ks * 32 + quad * 8);
#pragma unroll
      for (int mi = 0; mi < 4; ++mi)
#pragma unroll
        for (int ni = 0; ni < 4; ++ni)
          acc[mi][ni] = __builtin_amdgcn_mfma_f32_16x16x32_bf16(af[mi], bf_[ni], acc[mi][ni], 0, 0, 0);
    }
    __syncthreads();
  }
#pragma unroll
  for (int mi = 0; mi < 4; ++mi)
#pragma unroll
    for (int r = 0; r < 4; ++r) {
      int lrow = wm + mi * 16 + quad * 4 + r;
      int grow = m0 + lrow;
      if (grow < rows) {
        size_t ob = (size_t)(off + grow) * N;
#pragma unroll
        for (int ni = 0; ni < 4; ++ni) {
          int col = n0 + wn + ni * 16 + l15;
          float v = acc[mi][ni][r] + bias[(size_t)e * N + col];
          if (GELU) v = gelu_tanh(v);
          Out[ob + col] = (bf16)v;
        }
      }
    }
}

// ---------------- combine: out = x_resid + w0*y[s0] + w1*y[s1] ----------------
__global__ void combine_kernel(const float* __restrict__ xr, const bf16* __restrict__ y,
                               const float* __restrict__ top_w, const int* __restrict__ inv_slot,
                               float* __restrict__ out) {
  const int n = blockIdx.x, tid = threadIdx.x;
  const float w0 = top_w[n * 2], w1 = top_w[n * 2 + 1];
  const size_t s0 = (size_t)inv_slot[n * 2] * 1024;
  const size_t s1 = (size_t)inv_slot[n * 2 + 1] * 1024;
  const int c = tid * 4;
  const size_t base = (size_t)n * 1024 + c;
  float4 xv = *(const float4*)(xr + base);
  const bf16* y0 = y + s0 + c;
  const bf16* y1 = y + s1 + c;
  float4 o;
  o.x = xv.x + w0 * (float)y0[0] + w1 * (float)y1[0];
  o.y = xv.y + w0 * (float)y0[1] + w1 * (float)y1[1];
  o.z = xv.z + w0 * (float)y0[2] + w1 * (float)y1[2];
  o.w = xv.w + w0 * (float)y0[3] + w1 * (float)y1[3];
  *(float4*)(out + base) = o;
}

// ==================================================================================
extern "C" void kernel_launch(void* const* d_in, const int* in_sizes, int n_in, void* d_out,
                              int out_size, void* d_ws, size_t ws_size, hipStream_t stream) {
  const float* x = (const float*)d_in[0];
  const float* ln1_g = (const float*)d_in[1];
  const float* ln1_b = (const float*)d_in[2];
  const float* ln2_g = (const float*)d_in[3];
  const float* ln2_b = (const float*)d_in[4];
  const float* w_qkv = (const float*)d_in[5];
  const float* w_o = (const float*)d_in[6];
  const float* w_gate = (const float*)d_in[7];
  const float* w1 = (const float*)d_in[8];
  const float* b1 = (const float*)d_in[9];
  const float* w2 = (const float*)d_in[10];
  const float* b2 = (const float*)d_in[11];
  float* out = (float*)d_out;

  char* p = (char*)d_ws;
  auto take = [&](size_t bytes) {
    char* r = p;
    p += (bytes + 255) & ~(size_t)255;
    return r;
  };
  bf16* wqkvT_h = (bf16*)take((size_t)3072 * 1024 * 2);
  bf16* wqkvT_l = (bf16*)take((size_t)3072 * 1024 * 2);
  bf16* woT_h = (bf16*)take((size_t)1024 * 1024 * 2);
  bf16* woT_l = (bf16*)take((size_t)1024 * 1024 * 2);
  bf16* w1T = (bf16*)take((size_t)8 * 4096 * 1024 * 2);
  bf16* w2T = (bf16*)take((size_t)8 * 1024 * 4096 * 2);
  // region A: h_hi|h_lo|qkv_f32 (early) aliased with he (late) — lifetimes disjoint
  char* regionA = take(67108864);
  bf16* h_hi = (bf16*)regionA;
  bf16* h_lo = (bf16*)(regionA + 8388608);
  float* qkv = (float*)(regionA + 16777216);
  bf16* he = (bf16*)regionA;
  // region B: o_hi|o_lo (early) aliased with y (late)
  char* regionB = take(16777216);
  bf16* o_hi = (bf16*)regionB;
  bf16* o_lo = (bf16*)(regionB + 8388608);
  bf16* yb = (bf16*)regionB;
  float* x_resid = (float*)take((size_t)4096 * 1024 * 4);
  bf16* moe_b = (bf16*)take((size_t)4096 * 1024 * 2);
  float* top_w = (float*)take(4096 * 2 * 4);
  int* top_i = (int*)take(4096 * 2 * 4);
  int* counts = (int*)take(256);
  int* offs = (int*)take(256);
  int* cursor = (int*)take(256);
  int* expert_tok = (int*)take(8192 * 4);
  int* inv_slot = (int*)take(8192 * 4);

  // zero routing counters (ws is poisoned before each call)
  hipMemsetAsync(counts, 0, 768, stream);

  // weight transpose + bf16 split conversion
  transpose_cvt_kernel<<<dim3(96, 32, 1), 256, 0, stream>>>(w_qkv, wqkvT_h, wqkvT_l, 1024, 3072);
  transpose_cvt_kernel<<<dim3(32, 32, 1), 256, 0, stream>>>(w_o, woT_h, woT_l, 1024, 1024);
  transpose_cvt_kernel<<<dim3(128, 32, 8), 256, 0, stream>>>(w1, w1T, nullptr, 1024, 4096);
  transpose_cvt_kernel<<<dim3(32, 128, 8), 256, 0, stream>>>(w2, w2T, nullptr, 4096, 1024);

  // LN1 -> h (hi/lo)
  ln_split_kernel<<<4096, 256, 0, stream>>>(x, ln1_g, ln1_b, h_hi, h_lo);
  // QKV GEMM (x3 precision) -> fp32 qkv
  gemm_x3_kernel<<<dim3(24, 32, 1), 256, 0, stream>>>(h_hi, h_lo, wqkvT_h, wqkvT_l, nullptr, qkv,
                                                      4096, 3072, 1024);
  // causal attention (fp32) -> o (hi/lo)
  attn_kernel<<<dim3(128, 8, 1), 256, 0, stream>>>(qkv, o_hi, o_lo);
  // O-proj (x3) + residual -> x_resid fp32
  gemm_x3_kernel<<<dim3(8, 32, 1), 256, 0, stream>>>(o_hi, o_lo, woT_h, woT_l, x, x_resid, 4096,
                                                     1024, 1024);
  // LN2 + gate + top2 routing
  ln2_gate_kernel<<<4096, 256, 0, stream>>>(x_resid, ln2_g, ln2_b, w_gate, moe_b, top_w, top_i,
                                            counts);
  offsets_kernel<<<1, 64, 0, stream>>>(counts, offs);
  scatter_kernel<<<16, 256, 0, stream>>>(top_i, offs, cursor, expert_tok, inv_slot);
  // expert FFN: gather -> GELU(x*W1+b1) -> *W2+b2
  gemm_moe_kernel<1><<<dim3(32, 32, 8), 256, 0, stream>>>(moe_b, w1T, b1, counts, offs, expert_tok,
                                                          he, 4096, 1024);
  gemm_moe_kernel<0><<<dim3(8, 32, 8), 256, 0, stream>>>(he, w2T, b2, counts, offs, nullptr, yb,
                                                         1024, 4096);
  // combine + residual
  combine_kernel<<<4096, 256, 0, stream>>>(x_resid, yb, top_w, inv_slot, out);
}

// Round 2
// 1000.408 us; speedup vs baseline: 1.1213x; 1.1213x over previous
//
#include <hip/hip_runtime.h>

#define DEV static __device__ __forceinline__

typedef __bf16 bf16;
typedef __bf16 bf16x4 __attribute__((ext_vector_type(4)));
typedef __bf16 bf16x8 __attribute__((ext_vector_type(8)));
typedef float f32x4 __attribute__((ext_vector_type(4)));

static_assert(sizeof(bf16x8) == 16, "bf16x8 must be 16B");

#define MFMA16(a, b, c) __builtin_amdgcn_mfma_f32_16x16x32_bf16((a), (b), (c), 0, 0, 0)

// ---------------- async global->LDS, 16B/lane, wave-uniform LDS base ----------------
DEV void gll16(const void* g, void* l) {
  __builtin_amdgcn_global_load_lds(
      (const __attribute__((address_space(1))) unsigned int*)g,
      (__attribute__((address_space(3))) unsigned int*)l, 16, 0, 0);
}

// ---------------- transpose + fp32 -> bf16 (hi, optional lo) ----------------
// src: [z][R][C] fp32 ; dst hi/lo: [z][C][R] bf16
__global__ void transpose_cvt_kernel(const float* __restrict__ src, bf16* __restrict__ hi,
                                     bf16* __restrict__ lo, int R, int C) {
  __shared__ float t[32][33];
  const int z = blockIdx.z;
  const size_t zoff = (size_t)z * R * C;
  const int c0 = blockIdx.x * 32, r0 = blockIdx.y * 32;
  const int tid = threadIdx.x;
#pragma unroll
  for (int i = 0; i < 4; ++i) {
    int idx = tid + i * 256;
    int r = idx >> 5, c = idx & 31;
    t[r][c] = src[zoff + (size_t)(r0 + r) * C + (c0 + c)];
  }
  __syncthreads();
#pragma unroll
  for (int i = 0; i < 4; ++i) {
    int idx = tid + i * 256;
    int c = idx >> 5, r = idx & 31;
    float v = t[r][c];
    bf16 h = (bf16)v;
    size_t o = zoff + (size_t)(c0 + c) * R + (r0 + r);
    hi[o] = h;
    if (lo) lo[o] = (bf16)(v - (float)h);
  }
}

// ---------------- block reduction helper (2 values, 256 threads) ----------------
DEV void block_reduce2(float& a, float& b, float* red, int tid) {
#pragma unroll
  for (int m = 32; m >= 1; m >>= 1) {
    a += __shfl_xor(a, m);
    b += __shfl_xor(b, m);
  }
  if ((tid & 63) == 0) {
    red[(tid >> 6) * 2] = a;
    red[(tid >> 6) * 2 + 1] = b;
  }
  __syncthreads();
  a = red[0] + red[2] + red[4] + red[6];
  b = red[1] + red[3] + red[5] + red[7];
}

// ---------------- LayerNorm -> bf16 hi/lo split ----------------
__global__ void ln_split_kernel(const float* __restrict__ x, const float* __restrict__ g,
                                const float* __restrict__ bb, bf16* __restrict__ hi,
                                bf16* __restrict__ lo) {
  __shared__ float red[8];
  const int n = blockIdx.x, tid = threadIdx.x;
  const float* row = x + (size_t)n * 1024;
  float4 v = *(const float4*)(row + tid * 4);
  float s = v.x + v.y + v.z + v.w;
  float ss = v.x * v.x + v.y * v.y + v.z * v.z + v.w * v.w;
  block_reduce2(s, ss, red, tid);
  float mean = s * (1.f / 1024.f);
  float var = ss * (1.f / 1024.f) - mean * mean;
  float rstd = rsqrtf(var + 1e-5f);
  float vv[4] = {v.x, v.y, v.z, v.w};
#pragma unroll
  for (int c = 0; c < 4; ++c) {
    int col = tid * 4 + c;
    float y = (vv[c] - mean) * rstd * g[col] + bb[col];
    bf16 h = (bf16)y;
    size_t o = (size_t)n * 1024 + col;
    hi[o] = h;
    lo[o] = (bf16)(y - (float)h);
  }
}

// ---------------- x3-precision GEMM: C[M,N] = A[M,K] * B^T[N,K] (+ addend) ----------------
__global__ __launch_bounds__(256, 2) void gemm_x3_kernel(
    const bf16* __restrict__ Ah, const bf16* __restrict__ Al, const bf16* __restrict__ Bh,
    const bf16* __restrict__ Bl, const float* __restrict__ addend, float* __restrict__ C, int M,
    int N, int K) {
  __shared__ bf16 As_h[128 * 64];
  __shared__ bf16 As_l[128 * 64];
  __shared__ bf16 Bs_h[128 * 64];
  __shared__ bf16 Bs_l[128 * 64];
  const int tid = threadIdx.x;
  const int w = tid >> 6, lane = tid & 63;
  const int quad = lane >> 4, l15 = lane & 15;
  const int m0 = blockIdx.y * 128, n0 = blockIdx.x * 128;
  const int wm = (w >> 1) * 64, wn = (w & 1) * 64;
  const int r8 = lane >> 3, c8 = lane & 7;

  size_t gA[4], gB[4];
  unsigned lbase[4];
#pragma unroll
  for (int i = 0; i < 4; ++i) {
    int rr = ((w * 4 + i) << 3) + r8;
    gA[i] = (size_t)(m0 + rr) * K + (c8 << 3);
    gB[i] = (size_t)(n0 + rr) * K + (c8 << 3);
    lbase[i] = (unsigned)((w * 4 + i) << 9);
  }
  const f32x4 fz = {0.f, 0.f, 0.f, 0.f};
  f32x4 acc[4][4];
#pragma unroll
  for (int a = 0; a < 4; ++a)
#pragma unroll
    for (int b = 0; b < 4; ++b) acc[a][b] = fz;

  for (int k0 = 0; k0 < K; k0 += 64) {
#pragma unroll
    for (int i = 0; i < 4; ++i) {
      gll16(Ah + gA[i] + k0, As_h + lbase[i]);
      gll16(Al + gA[i] + k0, As_l + lbase[i]);
      gll16(Bh + gB[i] + k0, Bs_h + lbase[i]);
      gll16(Bl + gB[i] + k0, Bs_l + lbase[i]);
    }
    __syncthreads();
#pragma unroll
    for (int ks = 0; ks < 2; ++ks) {
      bf16x8 a_h[4], a_l[4], b_h[4], b_l[4];
#pragma unroll
      for (int mi = 0; mi < 4; ++mi) {
        int off = (wm + mi * 16 + l15) * 64 + ks * 32 + quad * 8;
        a_h[mi] = *(const bf16x8*)(As_h + off);
        a_l[mi] = *(const bf16x8*)(As_l + off);
      }
#pragma unroll
      for (int ni = 0; ni < 4; ++ni) {
        int off = (wn + ni * 16 + l15) * 64 + ks * 32 + quad * 8;
        b_h[ni] = *(const bf16x8*)(Bs_h + off);
        b_l[ni] = *(const bf16x8*)(Bs_l + off);
      }
#pragma unroll
      for (int mi = 0; mi < 4; ++mi)
#pragma unroll
        for (int ni = 0; ni < 4; ++ni) {
          acc[mi][ni] = MFMA16(a_h[mi], b_h[ni], acc[mi][ni]);
          acc[mi][ni] = MFMA16(a_h[mi], b_l[ni], acc[mi][ni]);
          acc[mi][ni] = MFMA16(a_l[mi], b_h[ni], acc[mi][ni]);
        }
    }
    __syncthreads();
  }
#pragma unroll
  for (int mi = 0; mi < 4; ++mi)
#pragma unroll
    for (int r = 0; r < 4; ++r) {
      int row = m0 + wm + mi * 16 + quad * 4 + r;
      size_t rb = (size_t)row * N;
#pragma unroll
      for (int ni = 0; ni < 4; ++ni) {
        int col = n0 + wn + ni * 16 + l15;
        float v = acc[mi][ni][r];
        if (addend) v += addend[rb + col];
        C[rb + col] = v;
      }
    }
}

// ---------------- K/V prep: split fp32 K,V into bf16 hi/lo, pre-tiled ----------------
// K out: [bh][t][kv_l 64][d 64], V out (transposed): [bh][t][d 64][kv_l 64]
__global__ __launch_bounds__(256) void kv_prep_kernel(const float* __restrict__ qkv,
                                                      bf16* __restrict__ Kh, bf16* __restrict__ Kl,
                                                      bf16* __restrict__ Vh, bf16* __restrict__ Vl) {
  __shared__ float vt[64 * 65];
  const int blk = blockIdx.x, tid = threadIdx.x;
  const int bh = blk >> 3, t = blk & 7;
  const int b = bh >> 4, h = bh & 15;
  const size_t tile = (size_t)blk * 4096;
#pragma unroll
  for (int it = 0; it < 4; ++it) {
    int fi = tid + it * 256;
    int r = fi >> 4, c4 = (fi & 15) << 2;
    const float* src = qkv + (size_t)(b * 512 + t * 64 + r) * 3072 + 1024 + h * 64 + c4;
    float4 kk4 = *(const float4*)src;
    float4 vv4 = *(const float4*)(src + 1024);
    float kk[4] = {kk4.x, kk4.y, kk4.z, kk4.w};
    float vv[4] = {vv4.x, vv4.y, vv4.z, vv4.w};
    bf16x4 h4, l4;
#pragma unroll
    for (int j = 0; j < 4; ++j) {
      bf16 hh = (bf16)kk[j];
      h4[j] = hh;
      l4[j] = (bf16)(kk[j] - (float)hh);
    }
    *(bf16x4*)(Kh + tile + r * 64 + c4) = h4;
    *(bf16x4*)(Kl + tile + r * 64 + c4) = l4;
#pragma unroll
    for (int j = 0; j < 4; ++j) vt[r * 65 + c4 + j] = vv[j];
  }
  __syncthreads();
#pragma unroll
  for (int it = 0; it < 4; ++it) {
    int fi = tid + it * 256;
    int d = fi >> 4, k4 = (fi & 15) << 2;
    bf16x4 h4, l4;
#pragma unroll
    for (int j = 0; j < 4; ++j) {
      float v = vt[(k4 + j) * 65 + d];
      bf16 hh = (bf16)v;
      h4[j] = hh;
      l4[j] = (bf16)(v - (float)hh);
    }
    *(bf16x4*)(Vh + tile + d * 64 + k4) = h4;
    *(bf16x4*)(Vl + tile + d * 64 + k4) = l4;
  }
}

// ---------------- MFMA flash attention (x4 hi/lo precision) ----------------
// Block: 4 waves, 64 q-rows per block (16 per wave). kv tiles of 64.
__global__ __launch_bounds__(256, 3) void attn_mfma_kernel(
    const float* __restrict__ qkv, const bf16* __restrict__ Kh, const bf16* __restrict__ Kl,
    const bf16* __restrict__ Vh, const bf16* __restrict__ Vl, bf16* __restrict__ o_hi,
    bf16* __restrict__ o_lo) {
  __shared__ bf16 Ks_h[4096], Ks_l[4096], Vs_h[4096], Vs_l[4096];
  __shared__ bf16 Ps_h[64 * 68], Ps_l[64 * 68];
  const int tid = threadIdx.x;
  const int w = tid >> 6, lane = tid & 63, quad = lane >> 4, l15 = lane & 15;
  const int bh = blockIdx.x & 127, qt = 7 - (blockIdx.x >> 7);  // heavy qt first
  const int b = bh >> 4, h = bh & 15;

  // Q fragments (A-layout), 1/8 scale folded, hi/lo split
  bf16x8 q_h[2], q_l[2];
  {
    const int qrow = b * 512 + qt * 64 + w * 16 + l15;
#pragma unroll
    for (int ks = 0; ks < 2; ++ks) {
      const float* src = qkv + (size_t)qrow * 3072 + h * 64 + ks * 32 + quad * 8;
      float4 v0 = *(const float4*)src, v1 = *(const float4*)(src + 4);
      float vv[8] = {v0.x, v0.y, v0.z, v0.w, v1.x, v1.y, v1.z, v1.w};
#pragma unroll
      for (int j = 0; j < 8; ++j) {
        float q = vv[j] * 0.125f;
        bf16 hh = (bf16)q;
        q_h[ks][j] = hh;
        q_l[ks][j] = (bf16)(q - (float)hh);
      }
    }
  }
  float m_r[4] = {-1e30f, -1e30f, -1e30f, -1e30f};
  float l_r[4] = {0.f, 0.f, 0.f, 0.f};
  const f32x4 fz = {0.f, 0.f, 0.f, 0.f};
  f32x4 acc[4] = {fz, fz, fz, fz};
  const size_t tb0 = (size_t)bh * 8 * 4096;

  for (int t = 0; t <= qt; ++t) {
    __syncthreads();  // protect K/V LDS from previous tile's readers
    {
      const size_t g = tb0 + (size_t)t * 4096;
#pragma unroll
      for (int i = 0; i < 2; ++i) {
        const int off = (w * 2 + i) << 9;  // wave-uniform; HW adds lane*16B
        gll16(Kh + g + off + lane * 8, Ks_h + off);
        gll16(Kl + g + off + lane * 8, Ks_l + off);
        gll16(Vh + g + off + lane * 8, Vs_h + off);
        gll16(Vl + g + off + lane * 8, Vs_l + off);
      }
    }
    __syncthreads();
    // S = Q K^T  (x4 split)
    f32x4 s[4];
#pragma unroll
    for (int nt = 0; nt < 4; ++nt) {
      s[nt] = fz;
#pragma unroll
      for (int ks = 0; ks < 2; ++ks) {
        const int ko = (nt * 16 + l15) * 64 + ks * 32 + quad * 8;
        bf16x8 kh = *(const bf16x8*)(Ks_h + ko);
        bf16x8 kl = *(const bf16x8*)(Ks_l + ko);
        s[nt] = MFMA16(q_h[ks], kh, s[nt]);
        s[nt] = MFMA16(q_h[ks], kl, s[nt]);
        s[nt] = MFMA16(q_l[ks], kh, s[nt]);
        s[nt] = MFMA16(q_l[ks], kl, s[nt]);
      }
    }
    if (t == qt) {  // diagonal tile causal mask: kv_local <= q_local
      const int qlr = w * 16 + quad * 4;
#pragma unroll
      for (int nt = 0; nt < 4; ++nt) {
        const int kvl = nt * 16 + l15;
#pragma unroll
        for (int r = 0; r < 4; ++r)
          if (kvl > qlr + r) s[nt][r] = -1e30f;
      }
    }
    // online softmax (rows = quad*4+r, cols across l15 lanes x 4 ntiles)
#pragma unroll
    for (int r = 0; r < 4; ++r) {
      float mx = fmaxf(fmaxf(s[0][r], s[1][r]), fmaxf(s[2][r], s[3][r]));
      mx = fmaxf(mx, __shfl_xor(mx, 1));
      mx = fmaxf(mx, __shfl_xor(mx, 2));
      mx = fmaxf(mx, __shfl_xor(mx, 4));
      mx = fmaxf(mx, __shfl_xor(mx, 8));
      const float mnew = fmaxf(m_r[r], mx);
      const float alpha = __expf(m_r[r] - mnew);
      m_r[r] = mnew;
      float rs = 0.f;
      const int pbase = (w * 16 + quad * 4 + r) * 68 + l15;  // stride 68: conflict-free writes
#pragma unroll
      for (int nt = 0; nt < 4; ++nt) {
        float p = __expf(s[nt][r] - mnew);
        rs += p;
        bf16 ph = (bf16)p;
        Ps_h[pbase + nt * 16] = ph;
        Ps_l[pbase + nt * 16] = (bf16)(p - (float)ph);
      }
      rs += __shfl_xor(rs, 1);
      rs += __shfl_xor(rs, 2);
      rs += __shfl_xor(rs, 4);
      rs += __shfl_xor(rs, 8);
      l_r[r] = l_r[r] * alpha + rs;
#pragma unroll
      for (int nt = 0; nt < 4; ++nt) acc[nt][r] *= alpha;
    }
    // O += P V  (x4 split; P read back in A-layout, per-wave rows only)
#pragma unroll
    for (int ks = 0; ks < 2; ++ks) {
      const int pb = (w * 16 + l15) * 68 + ks * 32 + quad * 8;
      bf16x4 ph0 = *(const bf16x4*)(Ps_h + pb), ph1 = *(const bf16x4*)(Ps_h + pb + 4);
      bf16x4 pl0 = *(const bf16x4*)(Ps_l + pb), pl1 = *(const bf16x4*)(Ps_l + pb + 4);
      bf16x8 pf_h, pf_l;
#pragma unroll
      for (int j = 0; j < 4; ++j) {
        pf_h[j] = ph0[j];
        pf_h[4 + j] = ph1[j];
        pf_l[j] = pl0[j];
        pf_l[4 + j] = pl1[j];
      }
#pragma unroll
      for (int nt = 0; nt < 4; ++nt) {
        const int vo = (nt * 16 + l15) * 64 + ks * 32 + quad * 8;
        bf16x8 vh = *(const bf16x8*)(Vs_h + vo);
        bf16x8 vl = *(const bf16x8*)(Vs_l + vo);
        acc[nt] = MFMA16(pf_h, vh, acc[nt]);
        acc[nt] = MFMA16(pf_h, vl, acc[nt]);
        acc[nt] = MFMA16(pf_l, vh, acc[nt]);
        acc[nt] = MFMA16(pf_l, vl, acc[nt]);
      }
    }
  }
  // epilogue: O /= l, hi/lo split out
  const int orow0 = b * 512 + qt * 64 + w * 16 + quad * 4;
#pragma unroll
  for (int r = 0; r < 4; ++r) {
    const float inv = 1.f / l_r[r];
    const size_t ob = (size_t)(orow0 + r) * 1024 + h * 64 + l15;
#pragma unroll
    for (int nt = 0; nt < 4; ++nt) {
      float v = acc[nt][r] * inv;
      bf16 hh = (bf16)v;
      o_hi[ob + nt * 16] = hh;
      o_lo[ob + nt * 16] = (bf16)(v - (float)hh);
    }
  }
}

// ---------------- LN2 + gate softmax + top2 routing ----------------
__global__ void ln2_gate_kernel(const float* __restrict__ xr, const float* __restrict__ g,
                                const float* __restrict__ bb, const float* __restrict__ wg,
                                bf16* __restrict__ moe_b, float* __restrict__ top_w,
                                int* __restrict__ top_i, int* __restrict__ counts) {
  __shared__ float red[8];
  __shared__ float red8[4][8];
  const int n = blockIdx.x, tid = threadIdx.x;
  const float* row = xr + (size_t)n * 1024;
  float4 v = *(const float4*)(row + tid * 4);
  float s = v.x + v.y + v.z + v.w;
  float ss = v.x * v.x + v.y * v.y + v.z * v.z + v.w * v.w;
  block_reduce2(s, ss, red, tid);
  float mean = s * (1.f / 1024.f);
  float var = ss * (1.f / 1024.f) - mean * mean;
  float rstd = rsqrtf(var + 1e-5f);
  float vv[4] = {v.x, v.y, v.z, v.w};
  float a8[8];
#pragma unroll
  for (int e = 0; e < 8; ++e) a8[e] = 0.f;
#pragma unroll
  for (int c = 0; c < 4; ++c) {
    int col = tid * 4 + c;
    float y = (vv[c] - mean) * rstd * g[col] + bb[col];
    moe_b[(size_t)n * 1024 + col] = (bf16)y;
    const float* wr = wg + (size_t)col * 8;
#pragma unroll
    for (int e = 0; e < 8; ++e) a8[e] += y * wr[e];
  }
#pragma unroll
  for (int e = 0; e < 8; ++e)
#pragma unroll
    for (int m = 32; m >= 1; m >>= 1) a8[e] += __shfl_xor(a8[e], m);
  if ((tid & 63) == 0)
#pragma unroll
    for (int e = 0; e < 8; ++e) red8[tid >> 6][e] = a8[e];
  __syncthreads();
  if (tid == 0) {
    float lg[8];
#pragma unroll
    for (int e = 0; e < 8; ++e) lg[e] = red8[0][e] + red8[1][e] + red8[2][e] + red8[3][e];
    float mx = lg[0];
#pragma unroll
    for (int e = 1; e < 8; ++e) mx = fmaxf(mx, lg[e]);
    float pe[8];
#pragma unroll
    for (int e = 0; e < 8; ++e) pe[e] = __expf(lg[e] - mx);
    int i1 = 0;
    float p1 = pe[0];
#pragma unroll
    for (int e = 1; e < 8; ++e)
      if (pe[e] > p1) { p1 = pe[e]; i1 = e; }
    int i2 = -1;
    float p2 = -1.f;
#pragma unroll
    for (int e = 0; e < 8; ++e)
      if (e != i1 && pe[e] > p2) { p2 = pe[e]; i2 = e; }
    float inv = 1.f / (p1 + p2);
    top_w[n * 2] = p1 * inv;
    top_w[n * 2 + 1] = p2 * inv;
    top_i[n * 2] = i1;
    top_i[n * 2 + 1] = i2;
    atomicAdd(&counts[i1], 1);
    atomicAdd(&counts[i2], 1);
  }
}

__global__ void offsets_kernel(const int* __restrict__ counts, int* __restrict__ offs) {
  if (threadIdx.x == 0 && blockIdx.x == 0) {
    int a = 0;
    for (int e = 0; e < 8; ++e) {
      offs[e] = a;
      a += counts[e];
    }
  }
}

__global__ void scatter_kernel(const int* __restrict__ top_i, const int* __restrict__ offs,
                               int* __restrict__ cursor, int* __restrict__ expert_tok,
                               int* __restrict__ inv_slot) {
  int n = blockIdx.x * 256 + threadIdx.x;
  if (n >= 4096) return;
#pragma unroll
  for (int k = 0; k < 2; ++k) {
    int e = top_i[n * 2 + k];
    int pos = atomicAdd(&cursor[e], 1);
    int slot = offs[e] + pos;
    expert_tok[slot] = n;
    inv_slot[n * 2 + k] = slot;
  }
}

DEV float gelu_tanh(float x) {
  float x3 = x * x * x;
  float t = tanhf(0.7978845608028654f * (x + 0.044715f * x3));
  return 0.5f * x * (1.f + t);
}

// ---------------- MoE GEMM ----------------
template <int GELU>
__global__ __launch_bounds__(256, 2) void gemm_moe_kernel(
    const bf16* __restrict__ A, const bf16* __restrict__ B, const float* __restrict__ bias,
    const int* __restrict__ counts, const int* __restrict__ offs, const int* __restrict__ gather,
    bf16* __restrict__ Out, int N, int K) {
  __shared__ bf16 As[128 * 64];
  __shared__ bf16 Bs[128 * 64];
  const int e = blockIdx.z;
  const int rows = counts[e];
  const int m0 = blockIdx.y * 128;
  if (m0 >= rows) return;
  const int off = offs[e];
  const int tid = threadIdx.x;
  const int w = tid >> 6, lane = tid & 63;
  const int quad = lane >> 4, l15 = lane & 15;
  const int n0 = blockIdx.x * 128;
  const int wm = (w >> 1) * 64, wn = (w & 1) * 64;
  const int r8 = lane >> 3, c8 = lane & 7;

  size_t gA[4], gB[4];
  unsigned lbase[4];
  const size_t bexp = (size_t)e * N * K;
#pragma unroll
  for (int i = 0; i < 4; ++i) {
    int rr = ((w * 4 + i) << 3) + r8;
    int lr = min(m0 + rr, rows - 1);
    int arow = gather ? gather[off + lr] : (off + lr);
    gA[i] = (size_t)arow * K + (c8 << 3);
    gB[i] = bexp + (size_t)(n0 + rr) * K + (c8 << 3);
    lbase[i] = (unsigned)((w * 4 + i) << 9);
  }
  const f32x4 fz = {0.f, 0.f, 0.f, 0.f};
  f32x4 acc[4][4];
#pragma unroll
  for (int a = 0; a < 4; ++a)
#pragma unroll
    for (int b = 0; b < 4; ++b) acc[a][b] = fz;

  for (int k0 = 0; k0 < K; k0 += 64) {
#pragma unroll
    for (int i = 0; i < 4; ++i) {
      gll16(A + gA[i] + k0, As + lbase[i]);
      gll16(B + gB[i] + k0, Bs + lbase[i]);
    }
    __syncthreads();
#pragma unroll
    for (int ks = 0; ks < 2; ++ks) {
      bf16x8 af[4], bf_[4];
#pragma unroll
      for (int mi = 0; mi < 4; ++mi)
        af[mi] = *(const bf16x8*)(As + (wm + mi * 16 + l15) * 64 + ks * 32 + quad * 8);
#pragma unroll
      for (int ni = 0; ni < 4; ++ni)
        bf_[ni] = *(const bf16x8*)(Bs + (wn + ni * 16 + l15) * 64 + ks * 32 + quad * 8);
#pragma unroll
      for (int mi = 0; mi < 4; ++mi)
#pragma unroll
        for (int ni = 0; ni < 4; ++ni) acc[mi][ni] = MFMA16(af[mi], bf_[ni], acc[mi][ni]);
    }
    __syncthreads();
  }
#pragma unroll
  for (int mi = 0; mi < 4; ++mi)
#pragma unroll
    for (int r = 0; r < 4; ++r) {
      int lrow = wm + mi * 16 + quad * 4 + r;
      int grow = m0 + lrow;
      if (grow < rows) {
        size_t ob = (size_t)(off + grow) * N;
#pragma unroll
        for (int ni = 0; ni < 4; ++ni) {
          int col = n0 + wn + ni * 16 + l15;
          float v = acc[mi][ni][r] + bias[(size_t)e * N + col];
          if (GELU) v = gelu_tanh(v);
          Out[ob + col] = (bf16)v;
        }
      }
    }
}

// ---------------- combine ----------------
__global__ void combine_kernel(const float* __restrict__ xr, const bf16* __restrict__ y,
                               const float* __restrict__ top_w, const int* __restrict__ inv_slot,
                               float* __restrict__ out) {
  const int n = blockIdx.x, tid = threadIdx.x;
  const float w0 = top_w[n * 2], w1 = top_w[n * 2 + 1];
  const size_t s0 = (size_t)inv_slot[n * 2] * 1024;
  const size_t s1 = (size_t)inv_slot[n * 2 + 1] * 1024;
  const int c = tid * 4;
  const size_t base = (size_t)n * 1024 + c;
  float4 xv = *(const float4*)(xr + base);
  const bf16* y0 = y + s0 + c;
  const bf16* y1 = y + s1 + c;
  float4 o;
  o.x = xv.x + w0 * (float)y0[0] + w1 * (float)y1[0];
  o.y = xv.y + w0 * (float)y0[1] + w1 * (float)y1[1];
  o.z = xv.z + w0 * (float)y0[2] + w1 * (float)y1[2];
  o.w = xv.w + w0 * (float)y0[3] + w1 * (float)y1[3];
  *(float4*)(out + base) = o;
}

// ==================================================================================
extern "C" void kernel_launch(void* const* d_in, const int* in_sizes, int n_in, void* d_out,
                              int out_size, void* d_ws, size_t ws_size, hipStream_t stream) {
  const float* x = (const float*)d_in[0];
  const float* ln1_g = (const float*)d_in[1];
  const float* ln1_b = (const float*)d_in[2];
  const float* ln2_g = (const float*)d_in[3];
  const float* ln2_b = (const float*)d_in[4];
  const float* w_qkv = (const float*)d_in[5];
  const float* w_o = (const float*)d_in[6];
  const float* w_gate = (const float*)d_in[7];
  const float* w1 = (const float*)d_in[8];
  const float* b1 = (const float*)d_in[9];
  const float* w2 = (const float*)d_in[10];
  const float* b2 = (const float*)d_in[11];
  float* out = (float*)d_out;

  char* p = (char*)d_ws;
  auto take = [&](size_t bytes) {
    char* r = p;
    p += (bytes + 255) & ~(size_t)255;
    return r;
  };
  bf16* wqkvT_h = (bf16*)take((size_t)3072 * 1024 * 2);
  bf16* wqkvT_l = (bf16*)take((size_t)3072 * 1024 * 2);
  bf16* woT_h = (bf16*)take((size_t)1024 * 1024 * 2);
  bf16* woT_l = (bf16*)take((size_t)1024 * 1024 * 2);
  bf16* w1T = (bf16*)take((size_t)8 * 4096 * 1024 * 2);
  bf16* w2T = (bf16*)take((size_t)8 * 1024 * 4096 * 2);
  // region A: h_hi|h_lo|qkv (early) aliased with he (late)
  char* regionA = take(67108864);
  bf16* h_hi = (bf16*)regionA;
  bf16* h_lo = (bf16*)(regionA + 8388608);
  float* qkv = (float*)(regionA + 16777216);
  bf16* he = (bf16*)regionA;
  // region B: o_hi|o_lo (early) aliased with yb (late)
  char* regionB = take(16777216);
  bf16* o_hi = (bf16*)regionB;
  bf16* o_lo = (bf16*)(regionB + 8388608);
  bf16* yb = (bf16*)regionB;
  // region C: Kh|Kl|Vh|Vl (attention) aliased with x_resid|moe_b (post-attention)
  char* regionC = take(33554432);
  bf16* Kh = (bf16*)regionC;
  bf16* Kl = (bf16*)(regionC + 8388608);
  bf16* Vh = (bf16*)(regionC + 16777216);
  bf16* Vl = (bf16*)(regionC + 25165824);
  float* x_resid = (float*)regionC;
  bf16* moe_b = (bf16*)(regionC + 16777216);
  float* top_w = (float*)take(4096 * 2 * 4);
  int* top_i = (int*)take(4096 * 2 * 4);
  int* counts = (int*)take(256);
  int* offs = (int*)take(256);
  int* cursor = (int*)take(256);
  int* expert_tok = (int*)take(8192 * 4);
  int* inv_slot = (int*)take(8192 * 4);

  hipMemsetAsync(counts, 0, 768, stream);  // counts+offs+cursor

  transpose_cvt_kernel<<<dim3(96, 32, 1), 256, 0, stream>>>(w_qkv, wqkvT_h, wqkvT_l, 1024, 3072);
  transpose_cvt_kernel<<<dim3(32, 32, 1), 256, 0, stream>>>(w_o, woT_h, woT_l, 1024, 1024);
  transpose_cvt_kernel<<<dim3(128, 32, 8), 256, 0, stream>>>(w1, w1T, nullptr, 1024, 4096);
  transpose_cvt_kernel<<<dim3(32, 128, 8), 256, 0, stream>>>(w2, w2T, nullptr, 4096, 1024);

  ln_split_kernel<<<4096, 256, 0, stream>>>(x, ln1_g, ln1_b, h_hi, h_lo);
  gemm_x3_kernel<<<dim3(24, 32, 1), 256, 0, stream>>>(h_hi, h_lo, wqkvT_h, wqkvT_l, nullptr, qkv,
                                                      4096, 3072, 1024);
  kv_prep_kernel<<<1024, 256, 0, stream>>>(qkv, Kh, Kl, Vh, Vl);
  attn_mfma_kernel<<<1024, 256, 0, stream>>>(qkv, Kh, Kl, Vh, Vl, o_hi, o_lo);
  gemm_x3_kernel<<<dim3(8, 32, 1), 256, 0, stream>>>(o_hi, o_lo, woT_h, woT_l, x, x_resid, 4096,
                                                     1024, 1024);
  ln2_gate_kernel<<<4096, 256, 0, stream>>>(x_resid, ln2_g, ln2_b, w_gate, moe_b, top_w, top_i,
                                            counts);
  offsets_kernel<<<1, 64, 0, stream>>>(counts, offs);
  scatter_kernel<<<16, 256, 0, stream>>>(top_i, offs, cursor, expert_tok, inv_slot);
  gemm_moe_kernel<1><<<dim3(32, 32, 8), 256, 0, stream>>>(moe_b, w1T, b1, counts, offs, expert_tok,
                                                          he, 4096, 1024);
  gemm_moe_kernel<0><<<dim3(8, 32, 8), 256, 0, stream>>>(he, w2T, b2, counts, offs, nullptr, yb,
                                                         1024, 4096);
  combine_kernel<<<4096, 256, 0, stream>>>(x_resid, yb, top_w, inv_slot, out);
}

// Round 3
// 919.576 us; speedup vs baseline: 1.2199x; 1.0879x over previous
//
#include <hip/hip_runtime.h>

#define DEV static __device__ __forceinline__

typedef __bf16 bf16;
typedef __bf16 bf16x4 __attribute__((ext_vector_type(4)));
typedef __bf16 bf16x8 __attribute__((ext_vector_type(8)));
typedef float f32x4 __attribute__((ext_vector_type(4)));

static_assert(sizeof(bf16x8) == 16, "bf16x8 must be 16B");

#define MFMA16(a, b, c) __builtin_amdgcn_mfma_f32_16x16x32_bf16((a), (b), (c), 0, 0, 0)

// ---------------- async global->LDS, 16B/lane, wave-uniform LDS base ----------------
DEV void gll16(const void* g, void* l) {
  __builtin_amdgcn_global_load_lds(
      (const __attribute__((address_space(1))) unsigned int*)g,
      (__attribute__((address_space(3))) unsigned int*)l, 16, 0, 0);
}

// ---------------- transpose + fp32 -> bf16 (hi, optional lo) ----------------
__global__ void transpose_cvt_kernel(const float* __restrict__ src, bf16* __restrict__ hi,
                                     bf16* __restrict__ lo, int R, int C) {
  __shared__ float t[32][33];
  const int z = blockIdx.z;
  const size_t zoff = (size_t)z * R * C;
  const int c0 = blockIdx.x * 32, r0 = blockIdx.y * 32;
  const int tid = threadIdx.x;
#pragma unroll
  for (int i = 0; i < 4; ++i) {
    int idx = tid + i * 256;
    int r = idx >> 5, c = idx & 31;
    t[r][c] = src[zoff + (size_t)(r0 + r) * C + (c0 + c)];
  }
  __syncthreads();
#pragma unroll
  for (int i = 0; i < 4; ++i) {
    int idx = tid + i * 256;
    int c = idx >> 5, r = idx & 31;
    float v = t[r][c];
    bf16 h = (bf16)v;
    size_t o = zoff + (size_t)(c0 + c) * R + (r0 + r);
    hi[o] = h;
    if (lo) lo[o] = (bf16)(v - (float)h);
  }
}

// ---------------- block reduction helper (2 values, 256 threads) ----------------
DEV void block_reduce2(float& a, float& b, float* red, int tid) {
#pragma unroll
  for (int m = 32; m >= 1; m >>= 1) {
    a += __shfl_xor(a, m);
    b += __shfl_xor(b, m);
  }
  if ((tid & 63) == 0) {
    red[(tid >> 6) * 2] = a;
    red[(tid >> 6) * 2 + 1] = b;
  }
  __syncthreads();
  a = red[0] + red[2] + red[4] + red[6];
  b = red[1] + red[3] + red[5] + red[7];
}

// ---------------- LayerNorm -> bf16 hi/lo split ----------------
__global__ void ln_split_kernel(const float* __restrict__ x, const float* __restrict__ g,
                                const float* __restrict__ bb, bf16* __restrict__ hi,
                                bf16* __restrict__ lo) {
  __shared__ float red[8];
  const int n = blockIdx.x, tid = threadIdx.x;
  const float* row = x + (size_t)n * 1024;
  float4 v = *(const float4*)(row + tid * 4);
  float s = v.x + v.y + v.z + v.w;
  float ss = v.x * v.x + v.y * v.y + v.z * v.z + v.w * v.w;
  block_reduce2(s, ss, red, tid);
  float mean = s * (1.f / 1024.f);
  float var = ss * (1.f / 1024.f) - mean * mean;
  float rstd = rsqrtf(var + 1e-5f);
  float vv[4] = {v.x, v.y, v.z, v.w};
#pragma unroll
  for (int c = 0; c < 4; ++c) {
    int col = tid * 4 + c;
    float y = (vv[c] - mean) * rstd * g[col] + bb[col];
    bf16 h = (bf16)y;
    size_t o = (size_t)n * 1024 + col;
    hi[o] = h;
    lo[o] = (bf16)(y - (float)h);
  }
}

// ---------------- x3-precision GEMM, BK=32 (32 KB LDS -> 5 blocks/CU) ----------------
// C[M,N] = (Ah+Al)[M,K] * (Bh+Bl)^T[N,K] (+ addend); acc = AhBh + AhBl + AlBh.
__global__ __launch_bounds__(256, 2) void gemm_x3_kernel(
    const bf16* __restrict__ Ah, const bf16* __restrict__ Al, const bf16* __restrict__ Bh,
    const bf16* __restrict__ Bl, const float* __restrict__ addend, float* __restrict__ C, int M,
    int N, int K) {
  __shared__ bf16 As_h[128 * 32];
  __shared__ bf16 As_l[128 * 32];
  __shared__ bf16 Bs_h[128 * 32];
  __shared__ bf16 Bs_l[128 * 32];
  const int tid = threadIdx.x;
  const int w = tid >> 6, lane = tid & 63;
  const int quad = lane >> 4, l15 = lane & 15;
  const int m0 = blockIdx.y * 128, n0 = blockIdx.x * 128;
  const int wm = (w >> 1) * 64, wn = (w & 1) * 64;
  const int r4 = lane >> 2, c4 = lane & 3;  // 16 rows x 4 col-chunks of 8 per gll16

  size_t gA[2], gB[2];
  unsigned lbase[2];
#pragma unroll
  for (int i = 0; i < 2; ++i) {
    int rr = (w * 2 + i) * 16 + r4;
    gA[i] = (size_t)(m0 + rr) * K + (c4 << 3);
    gB[i] = (size_t)(n0 + rr) * K + (c4 << 3);
    lbase[i] = (unsigned)((w * 2 + i) << 9);
  }
  const f32x4 fz = {0.f, 0.f, 0.f, 0.f};
  f32x4 acc[4][4];
#pragma unroll
  for (int a = 0; a < 4; ++a)
#pragma unroll
    for (int b = 0; b < 4; ++b) acc[a][b] = fz;

  for (int k0 = 0; k0 < K; k0 += 32) {
#pragma unroll
    for (int i = 0; i < 2; ++i) {
      gll16(Ah + gA[i] + k0, As_h + lbase[i]);
      gll16(Al + gA[i] + k0, As_l + lbase[i]);
      gll16(Bh + gB[i] + k0, Bs_h + lbase[i]);
      gll16(Bl + gB[i] + k0, Bs_l + lbase[i]);
    }
    __syncthreads();
    bf16x8 a_h[4], a_l[4], b_h[4], b_l[4];
#pragma unroll
    for (int mi = 0; mi < 4; ++mi) {
      int off = (wm + mi * 16 + l15) * 32 + quad * 8;
      a_h[mi] = *(const bf16x8*)(As_h + off);
      a_l[mi] = *(const bf16x8*)(As_l + off);
    }
#pragma unroll
    for (int ni = 0; ni < 4; ++ni) {
      int off = (wn + ni * 16 + l15) * 32 + quad * 8;
      b_h[ni] = *(const bf16x8*)(Bs_h + off);
      b_l[ni] = *(const bf16x8*)(Bs_l + off);
    }
#pragma unroll
    for (int mi = 0; mi < 4; ++mi)
#pragma unroll
      for (int ni = 0; ni < 4; ++ni) {
        acc[mi][ni] = MFMA16(a_h[mi], b_h[ni], acc[mi][ni]);
        acc[mi][ni] = MFMA16(a_h[mi], b_l[ni], acc[mi][ni]);
        acc[mi][ni] = MFMA16(a_l[mi], b_h[ni], acc[mi][ni]);
      }
    __syncthreads();
  }
#pragma unroll
  for (int mi = 0; mi < 4; ++mi)
#pragma unroll
    for (int r = 0; r < 4; ++r) {
      int row = m0 + wm + mi * 16 + quad * 4 + r;
      size_t rb = (size_t)row * N;
#pragma unroll
      for (int ni = 0; ni < 4; ++ni) {
        int col = n0 + wn + ni * 16 + l15;
        float v = acc[mi][ni][r];
        if (addend) v += addend[rb + col];
        C[rb + col] = v;
      }
    }
}

// ---------------- K/V prep: split fp32 K,V into bf16 hi/lo, pre-tiled ----------------
__global__ __launch_bounds__(256) void kv_prep_kernel(const float* __restrict__ qkv,
                                                      bf16* __restrict__ Kh, bf16* __restrict__ Kl,
                                                      bf16* __restrict__ Vh, bf16* __restrict__ Vl) {
  __shared__ float vt[64 * 65];
  const int blk = blockIdx.x, tid = threadIdx.x;
  const int bh = blk >> 3, t = blk & 7;
  const int b = bh >> 4, h = bh & 15;
  const size_t tile = (size_t)blk * 4096;
#pragma unroll
  for (int it = 0; it < 4; ++it) {
    int fi = tid + it * 256;
    int r = fi >> 4, c4 = (fi & 15) << 2;
    const float* src = qkv + (size_t)(b * 512 + t * 64 + r) * 3072 + 1024 + h * 64 + c4;
    float4 kk4 = *(const float4*)src;
    float4 vv4 = *(const float4*)(src + 1024);
    float kk[4] = {kk4.x, kk4.y, kk4.z, kk4.w};
    float vv[4] = {vv4.x, vv4.y, vv4.z, vv4.w};
    bf16x4 h4, l4;
#pragma unroll
    for (int j = 0; j < 4; ++j) {
      bf16 hh = (bf16)kk[j];
      h4[j] = hh;
      l4[j] = (bf16)(kk[j] - (float)hh);
    }
    *(bf16x4*)(Kh + tile + r * 64 + c4) = h4;
    *(bf16x4*)(Kl + tile + r * 64 + c4) = l4;
#pragma unroll
    for (int j = 0; j < 4; ++j) vt[r * 65 + c4 + j] = vv[j];
  }
  __syncthreads();
#pragma unroll
  for (int it = 0; it < 4; ++it) {
    int fi = tid + it * 256;
    int d = fi >> 4, k4 = (fi & 15) << 2;
    bf16x4 h4, l4;
#pragma unroll
    for (int j = 0; j < 4; ++j) {
      float v = vt[(k4 + j) * 65 + d];
      bf16 hh = (bf16)v;
      h4[j] = hh;
      l4[j] = (bf16)(v - (float)hh);
    }
    *(bf16x4*)(Vh + tile + d * 64 + k4) = h4;
    *(bf16x4*)(Vl + tile + d * 64 + k4) = l4;
  }
}

// ---------------- MFMA flash attention (x4 hi/lo precision) ----------------
__global__ __launch_bounds__(256, 3) void attn_mfma_kernel(
    const float* __restrict__ qkv, const bf16* __restrict__ Kh, const bf16* __restrict__ Kl,
    const bf16* __restrict__ Vh, const bf16* __restrict__ Vl, bf16* __restrict__ o_hi,
    bf16* __restrict__ o_lo) {
  __shared__ bf16 Ks_h[4096], Ks_l[4096], Vs_h[4096], Vs_l[4096];
  __shared__ bf16 Ps_h[64 * 68], Ps_l[64 * 68];
  const int tid = threadIdx.x;
  const int w = tid >> 6, lane = tid & 63, quad = lane >> 4, l15 = lane & 15;
  const int bh = blockIdx.x & 127, qt = 7 - (blockIdx.x >> 7);  // heavy qt first
  const int b = bh >> 4, h = bh & 15;

  bf16x8 q_h[2], q_l[2];
  {
    const int qrow = b * 512 + qt * 64 + w * 16 + l15;
#pragma unroll
    for (int ks = 0; ks < 2; ++ks) {
      const float* src = qkv + (size_t)qrow * 3072 + h * 64 + ks * 32 + quad * 8;
      float4 v0 = *(const float4*)src, v1 = *(const float4*)(src + 4);
      float vv[8] = {v0.x, v0.y, v0.z, v0.w, v1.x, v1.y, v1.z, v1.w};
#pragma unroll
      for (int j = 0; j < 8; ++j) {
        float q = vv[j] * 0.125f;
        bf16 hh = (bf16)q;
        q_h[ks][j] = hh;
        q_l[ks][j] = (bf16)(q - (float)hh);
      }
    }
  }
  float m_r[4] = {-1e30f, -1e30f, -1e30f, -1e30f};
  float l_r[4] = {0.f, 0.f, 0.f, 0.f};
  const f32x4 fz = {0.f, 0.f, 0.f, 0.f};
  f32x4 acc[4] = {fz, fz, fz, fz};
  const size_t tb0 = (size_t)bh * 8 * 4096;

  for (int t = 0; t <= qt; ++t) {
    __syncthreads();
    {
      const size_t g = tb0 + (size_t)t * 4096;
#pragma unroll
      for (int i = 0; i < 2; ++i) {
        const int off = (w * 2 + i) << 9;
        gll16(Kh + g + off + lane * 8, Ks_h + off);
        gll16(Kl + g + off + lane * 8, Ks_l + off);
        gll16(Vh + g + off + lane * 8, Vs_h + off);
        gll16(Vl + g + off + lane * 8, Vs_l + off);
      }
    }
    __syncthreads();
    f32x4 s[4];
#pragma unroll
    for (int nt = 0; nt < 4; ++nt) {
      s[nt] = fz;
#pragma unroll
      for (int ks = 0; ks < 2; ++ks) {
        const int ko = (nt * 16 + l15) * 64 + ks * 32 + quad * 8;
        bf16x8 kh = *(const bf16x8*)(Ks_h + ko);
        bf16x8 kl = *(const bf16x8*)(Ks_l + ko);
        s[nt] = MFMA16(q_h[ks], kh, s[nt]);
        s[nt] = MFMA16(q_h[ks], kl, s[nt]);
        s[nt] = MFMA16(q_l[ks], kh, s[nt]);
        s[nt] = MFMA16(q_l[ks], kl, s[nt]);
      }
    }
    if (t == qt) {
      const int qlr = w * 16 + quad * 4;
#pragma unroll
      for (int nt = 0; nt < 4; ++nt) {
        const int kvl = nt * 16 + l15;
#pragma unroll
        for (int r = 0; r < 4; ++r)
          if (kvl > qlr + r) s[nt][r] = -1e30f;
      }
    }
#pragma unroll
    for (int r = 0; r < 4; ++r) {
      float mx = fmaxf(fmaxf(s[0][r], s[1][r]), fmaxf(s[2][r], s[3][r]));
      mx = fmaxf(mx, __shfl_xor(mx, 1));
      mx = fmaxf(mx, __shfl_xor(mx, 2));
      mx = fmaxf(mx, __shfl_xor(mx, 4));
      mx = fmaxf(mx, __shfl_xor(mx, 8));
      const float mnew = fmaxf(m_r[r], mx);
      const float alpha = __expf(m_r[r] - mnew);
      m_r[r] = mnew;
      float rs = 0.f;
      const int pbase = (w * 16 + quad * 4 + r) * 68 + l15;
#pragma unroll
      for (int nt = 0; nt < 4; ++nt) {
        float p = __expf(s[nt][r] - mnew);
        rs += p;
        bf16 ph = (bf16)p;
        Ps_h[pbase + nt * 16] = ph;
        Ps_l[pbase + nt * 16] = (bf16)(p - (float)ph);
      }
      rs += __shfl_xor(rs, 1);
      rs += __shfl_xor(rs, 2);
      rs += __shfl_xor(rs, 4);
      rs += __shfl_xor(rs, 8);
      l_r[r] = l_r[r] * alpha + rs;
#pragma unroll
      for (int nt = 0; nt < 4; ++nt) acc[nt][r] *= alpha;
    }
#pragma unroll
    for (int ks = 0; ks < 2; ++ks) {
      const int pb = (w * 16 + l15) * 68 + ks * 32 + quad * 8;
      bf16x4 ph0 = *(const bf16x4*)(Ps_h + pb), ph1 = *(const bf16x4*)(Ps_h + pb + 4);
      bf16x4 pl0 = *(const bf16x4*)(Ps_l + pb), pl1 = *(const bf16x4*)(Ps_l + pb + 4);
      bf16x8 pf_h, pf_l;
#pragma unroll
      for (int j = 0; j < 4; ++j) {
        pf_h[j] = ph0[j];
        pf_h[4 + j] = ph1[j];
        pf_l[j] = pl0[j];
        pf_l[4 + j] = pl1[j];
      }
#pragma unroll
      for (int nt = 0; nt < 4; ++nt) {
        const int vo = (nt * 16 + l15) * 64 + ks * 32 + quad * 8;
        bf16x8 vh = *(const bf16x8*)(Vs_h + vo);
        bf16x8 vl = *(const bf16x8*)(Vs_l + vo);
        acc[nt] = MFMA16(pf_h, vh, acc[nt]);
        acc[nt] = MFMA16(pf_h, vl, acc[nt]);
        acc[nt] = MFMA16(pf_l, vh, acc[nt]);
        acc[nt] = MFMA16(pf_l, vl, acc[nt]);
      }
    }
  }
  const int orow0 = b * 512 + qt * 64 + w * 16 + quad * 4;
#pragma unroll
  for (int r = 0; r < 4; ++r) {
    const float inv = 1.f / l_r[r];
    const size_t ob = (size_t)(orow0 + r) * 1024 + h * 64 + l15;
#pragma unroll
    for (int nt = 0; nt < 4; ++nt) {
      float v = acc[nt][r] * inv;
      bf16 hh = (bf16)v;
      o_hi[ob + nt * 16] = hh;
      o_lo[ob + nt * 16] = (bf16)(v - (float)hh);
    }
  }
}

// ---------------- LN2 + gate softmax + top2 routing ----------------
__global__ void ln2_gate_kernel(const float* __restrict__ xr, const float* __restrict__ g,
                                const float* __restrict__ bb, const float* __restrict__ wg,
                                bf16* __restrict__ moe_b, float* __restrict__ top_w,
                                int* __restrict__ top_i, int* __restrict__ counts) {
  __shared__ float red[8];
  __shared__ float red8[4][8];
  const int n = blockIdx.x, tid = threadIdx.x;
  const float* row = xr + (size_t)n * 1024;
  float4 v = *(const float4*)(row + tid * 4);
  float s = v.x + v.y + v.z + v.w;
  float ss = v.x * v.x + v.y * v.y + v.z * v.z + v.w * v.w;
  block_reduce2(s, ss, red, tid);
  float mean = s * (1.f / 1024.f);
  float var = ss * (1.f / 1024.f) - mean * mean;
  float rstd = rsqrtf(var + 1e-5f);
  float vv[4] = {v.x, v.y, v.z, v.w};
  float a8[8];
#pragma unroll
  for (int e = 0; e < 8; ++e) a8[e] = 0.f;
#pragma unroll
  for (int c = 0; c < 4; ++c) {
    int col = tid * 4 + c;
    float y = (vv[c] - mean) * rstd * g[col] + bb[col];
    moe_b[(size_t)n * 1024 + col] = (bf16)y;
    const float* wr = wg + (size_t)col * 8;
#pragma unroll
    for (int e = 0; e < 8; ++e) a8[e] += y * wr[e];
  }
#pragma unroll
  for (int e = 0; e < 8; ++e)
#pragma unroll
    for (int m = 32; m >= 1; m >>= 1) a8[e] += __shfl_xor(a8[e], m);
  if ((tid & 63) == 0)
#pragma unroll
    for (int e = 0; e < 8; ++e) red8[tid >> 6][e] = a8[e];
  __syncthreads();
  if (tid == 0) {
    float lg[8];
#pragma unroll
    for (int e = 0; e < 8; ++e) lg[e] = red8[0][e] + red8[1][e] + red8[2][e] + red8[3][e];
    float mx = lg[0];
#pragma unroll
    for (int e = 1; e < 8; ++e) mx = fmaxf(mx, lg[e]);
    float pe[8];
#pragma unroll
    for (int e = 0; e < 8; ++e) pe[e] = __expf(lg[e] - mx);
    int i1 = 0;
    float p1 = pe[0];
#pragma unroll
    for (int e = 1; e < 8; ++e)
      if (pe[e] > p1) { p1 = pe[e]; i1 = e; }
    int i2 = -1;
    float p2 = -1.f;
#pragma unroll
    for (int e = 0; e < 8; ++e)
      if (e != i1 && pe[e] > p2) { p2 = pe[e]; i2 = e; }
    float inv = 1.f / (p1 + p2);
    top_w[n * 2] = p1 * inv;
    top_w[n * 2 + 1] = p2 * inv;
    top_i[n * 2] = i1;
    top_i[n * 2 + 1] = i2;
    atomicAdd(&counts[i1], 1);
    atomicAdd(&counts[i2], 1);
  }
}

__global__ void offsets_kernel(const int* __restrict__ counts, int* __restrict__ offs) {
  if (threadIdx.x == 0 && blockIdx.x == 0) {
    int a = 0;
    for (int e = 0; e < 8; ++e) {
      offs[e] = a;
      a += counts[e];
    }
  }
}

__global__ void scatter_kernel(const int* __restrict__ top_i, const int* __restrict__ offs,
                               int* __restrict__ cursor, int* __restrict__ expert_tok,
                               int* __restrict__ inv_slot) {
  int n = blockIdx.x * 256 + threadIdx.x;
  if (n >= 4096) return;
#pragma unroll
  for (int k = 0; k < 2; ++k) {
    int e = top_i[n * 2 + k];
    int pos = atomicAdd(&cursor[e], 1);
    int slot = offs[e] + pos;
    expert_tok[slot] = n;
    inv_slot[n * 2 + k] = slot;
  }
}

// gelu(x) = x * sigmoid(1.5957691216057308*(x + 0.044715 x^3)) — identical to tanh form
DEV float gelu_fast(float x) {
  float u2 = 1.5957691216057308f * (x + 0.044715f * x * x * x);
  return x / (1.f + __expf(-u2));
}

// ---------------- MoE GEMM (grid: x=expert FASTEST, y=n-block, z=m-block) ----------------
template <int GELU>
__global__ __launch_bounds__(256, 2) void gemm_moe_kernel(
    const bf16* __restrict__ A, const bf16* __restrict__ B, const float* __restrict__ bias,
    const int* __restrict__ counts, const int* __restrict__ offs, const int* __restrict__ gather,
    bf16* __restrict__ Out, int N, int K) {
  __shared__ bf16 As[128 * 64];
  __shared__ bf16 Bs[128 * 64];
  const int e = blockIdx.x;
  const int rows = counts[e];
  const int m0 = blockIdx.z * 128;
  if (m0 >= rows) return;
  const int off = offs[e];
  const int tid = threadIdx.x;
  const int w = tid >> 6, lane = tid & 63;
  const int quad = lane >> 4, l15 = lane & 15;
  const int n0 = blockIdx.y * 128;
  const int wm = (w >> 1) * 64, wn = (w & 1) * 64;
  const int r8 = lane >> 3, c8 = lane & 7;

  size_t gA[4], gB[4];
  unsigned lbase[4];
  const size_t bexp = (size_t)e * N * K;
#pragma unroll
  for (int i = 0; i < 4; ++i) {
    int rr = ((w * 4 + i) << 3) + r8;
    int lr = min(m0 + rr, rows - 1);
    int arow = gather ? gather[off + lr] : (off + lr);
    gA[i] = (size_t)arow * K + (c8 << 3);
    gB[i] = bexp + (size_t)(n0 + rr) * K + (c8 << 3);
    lbase[i] = (unsigned)((w * 4 + i) << 9);
  }
  const f32x4 fz = {0.f, 0.f, 0.f, 0.f};
  f32x4 acc[4][4];
#pragma unroll
  for (int a = 0; a < 4; ++a)
#pragma unroll
    for (int b = 0; b < 4; ++b) acc[a][b] = fz;

  for (int k0 = 0; k0 < K; k0 += 64) {
#pragma unroll
    for (int i = 0; i < 4; ++i) {
      gll16(A + gA[i] + k0, As + lbase[i]);
      gll16(B + gB[i] + k0, Bs + lbase[i]);
    }
    __syncthreads();
#pragma unroll
    for (int ks = 0; ks < 2; ++ks) {
      bf16x8 af[4], bf_[4];
#pragma unroll
      for (int mi = 0; mi < 4; ++mi)
        af[mi] = *(const bf16x8*)(As + (wm + mi * 16 + l15) * 64 + ks * 32 + quad * 8);
#pragma unroll
      for (int ni = 0; ni < 4; ++ni)
        bf_[ni] = *(const bf16x8*)(Bs + (wn + ni * 16 + l15) * 64 + ks * 32 + quad * 8);
#pragma unroll
      for (int mi = 0; mi < 4; ++mi)
#pragma unroll
        for (int ni = 0; ni < 4; ++ni) acc[mi][ni] = MFMA16(af[mi], bf_[ni], acc[mi][ni]);
    }
    __syncthreads();
  }
#pragma unroll
  for (int mi = 0; mi < 4; ++mi)
#pragma unroll
    for (int r = 0; r < 4; ++r) {
      int lrow = wm + mi * 16 + quad * 4 + r;
      int grow = m0 + lrow;
      if (grow < rows) {
        size_t ob = (size_t)(off + grow) * N;
#pragma unroll
        for (int ni = 0; ni < 4; ++ni) {
          int col = n0 + wn + ni * 16 + l15;
          float v = acc[mi][ni][r] + bias[(size_t)e * N + col];
          if (GELU) v = gelu_fast(v);
          Out[ob + col] = (bf16)v;
        }
      }
    }
}

// ---------------- combine ----------------
__global__ void combine_kernel(const float* __restrict__ xr, const bf16* __restrict__ y,
                               const float* __restrict__ top_w, const int* __restrict__ inv_slot,
                               float* __restrict__ out) {
  const int n = blockIdx.x, tid = threadIdx.x;
  const float w0 = top_w[n * 2], w1 = top_w[n * 2 + 1];
  const size_t s0 = (size_t)inv_slot[n * 2] * 1024;
  const size_t s1 = (size_t)inv_slot[n * 2 + 1] * 1024;
  const int c = tid * 4;
  const size_t base = (size_t)n * 1024 + c;
  float4 xv = *(const float4*)(xr + base);
  const bf16* y0 = y + s0 + c;
  const bf16* y1 = y + s1 + c;
  float4 o;
  o.x = xv.x + w0 * (float)y0[0] + w1 * (float)y1[0];
  o.y = xv.y + w0 * (float)y0[1] + w1 * (float)y1[1];
  o.z = xv.z + w0 * (float)y0[2] + w1 * (float)y1[2];
  o.w = xv.w + w0 * (float)y0[3] + w1 * (float)y1[3];
  *(float4*)(out + base) = o;
}

// ==================================================================================
extern "C" void kernel_launch(void* const* d_in, const int* in_sizes, int n_in, void* d_out,
                              int out_size, void* d_ws, size_t ws_size, hipStream_t stream) {
  const float* x = (const float*)d_in[0];
  const float* ln1_g = (const float*)d_in[1];
  const float* ln1_b = (const float*)d_in[2];
  const float* ln2_g = (const float*)d_in[3];
  const float* ln2_b = (const float*)d_in[4];
  const float* w_qkv = (const float*)d_in[5];
  const float* w_o = (const float*)d_in[6];
  const float* w_gate = (const float*)d_in[7];
  const float* w1 = (const float*)d_in[8];
  const float* b1 = (const float*)d_in[9];
  const float* w2 = (const float*)d_in[10];
  const float* b2 = (const float*)d_in[11];
  float* out = (float*)d_out;

  char* p = (char*)d_ws;
  auto take = [&](size_t bytes) {
    char* r = p;
    p += (bytes + 255) & ~(size_t)255;
    return r;
  };
  bf16* wqkvT_h = (bf16*)take((size_t)3072 * 1024 * 2);
  bf16* wqkvT_l = (bf16*)take((size_t)3072 * 1024 * 2);
  bf16* woT_h = (bf16*)take((size_t)1024 * 1024 * 2);
  bf16* woT_l = (bf16*)take((size_t)1024 * 1024 * 2);
  bf16* w1T = (bf16*)take((size_t)8 * 4096 * 1024 * 2);
  bf16* w2T = (bf16*)take((size_t)8 * 1024 * 4096 * 2);
  char* regionA = take(67108864);
  bf16* h_hi = (bf16*)regionA;
  bf16* h_lo = (bf16*)(regionA + 8388608);
  float* qkv = (float*)(regionA + 16777216);
  bf16* he = (bf16*)regionA;
  char* regionB = take(16777216);
  bf16* o_hi = (bf16*)regionB;
  bf16* o_lo = (bf16*)(regionB + 8388608);
  bf16* yb = (bf16*)regionB;
  char* regionC = take(33554432);
  bf16* Kh = (bf16*)regionC;
  bf16* Kl = (bf16*)(regionC + 8388608);
  bf16* Vh = (bf16*)(regionC + 16777216);
  bf16* Vl = (bf16*)(regionC + 25165824);
  float* x_resid = (float*)regionC;
  bf16* moe_b = (bf16*)(regionC + 16777216);
  float* top_w = (float*)take(4096 * 2 * 4);
  int* top_i = (int*)take(4096 * 2 * 4);
  int* counts = (int*)take(256);
  int* offs = (int*)take(256);
  int* cursor = (int*)take(256);
  int* expert_tok = (int*)take(8192 * 4);
  int* inv_slot = (int*)take(8192 * 4);

  hipMemsetAsync(counts, 0, 768, stream);  // counts+offs+cursor

  transpose_cvt_kernel<<<dim3(96, 32, 1), 256, 0, stream>>>(w_qkv, wqkvT_h, wqkvT_l, 1024, 3072);
  transpose_cvt_kernel<<<dim3(32, 32, 1), 256, 0, stream>>>(w_o, woT_h, woT_l, 1024, 1024);
  transpose_cvt_kernel<<<dim3(128, 32, 8), 256, 0, stream>>>(w1, w1T, nullptr, 1024, 4096);
  transpose_cvt_kernel<<<dim3(32, 128, 8), 256, 0, stream>>>(w2, w2T, nullptr, 4096, 1024);

  ln_split_kernel<<<4096, 256, 0, stream>>>(x, ln1_g, ln1_b, h_hi, h_lo);
  gemm_x3_kernel<<<dim3(24, 32, 1), 256, 0, stream>>>(h_hi, h_lo, wqkvT_h, wqkvT_l, nullptr, qkv,
                                                      4096, 3072, 1024);
  kv_prep_kernel<<<1024, 256, 0, stream>>>(qkv, Kh, Kl, Vh, Vl);
  attn_mfma_kernel<<<1024, 256, 0, stream>>>(qkv, Kh, Kl, Vh, Vl, o_hi, o_lo);
  gemm_x3_kernel<<<dim3(8, 32, 1), 256, 0, stream>>>(o_hi, o_lo, woT_h, woT_l, x, x_resid, 4096,
                                                     1024, 1024);
  ln2_gate_kernel<<<4096, 256, 0, stream>>>(x_resid, ln2_g, ln2_b, w_gate, moe_b, top_w, top_i,
                                            counts);
  offsets_kernel<<<1, 64, 0, stream>>>(counts, offs);
  scatter_kernel<<<16, 256, 0, stream>>>(top_i, offs, cursor, expert_tok, inv_slot);
  // expert dim fastest: active blocks dispatch first and interleave across CUs
  gemm_moe_kernel<1><<<dim3(8, 32, 12), 256, 0, stream>>>(moe_b, w1T, b1, counts, offs, expert_tok,
                                                          he, 4096, 1024);
  gemm_moe_kernel<0><<<dim3(8, 8, 12), 256, 0, stream>>>(he, w2T, b2, counts, offs, nullptr, yb,
                                                         1024, 4096);
  combine_kernel<<<4096, 256, 0, stream>>>(x_resid, yb, top_w, inv_slot, out);
}